// Round 6
// baseline (1384.080 us; speedup 1.0000x reference)
//
#include <hip/hip_runtime.h>

// CapsuleNet forward, fused, fp32 — R6: R5 + __launch_bounds__(768, 6).
// R3 vs R4/R5 evidence: with 12-wave blocks and ~80 KB LDS, the scheduler
// co-schedules 2 blocks/CU ONLY when min-waves/EU=6 is declared (R3: 65%
// occupancy; R4/R5: 35%). The 6-waves/EU VGPR cap is ~85 (512 VGPR/SIMD
// pool); R5's natural allocation is 64, so unlike R3 this declaration
// forces no spill. Everything else identical to R5: register-resident
// routing (wave=o, lane=(iq,d)), DPP row16 allreduce for d-sums,
// __shfl_xor for iq-sums, per-iter LDS limited to the softmax-over-o
// exchange, einsum with lin_w streamed from L2 per batch pair.
constexpr int OC = 10, NI = 36, OD = 16, IL = 8;
constexpr int M_BLK = 8;     // batches per block
constexpr int NT    = 768;   // 12 waves
constexpr int CROW  = 12;    // caps row stride (16B aligned, 8 b128 start banks)
constexpr int SROW  = 20;    // spl row stride

template <int CTRL>
__device__ __forceinline__ float dpp_ror_add(float x) {
    int yi = __builtin_amdgcn_update_dpp(0, __float_as_int(x), CTRL, 0xf, 0xf, false);
    return x + __int_as_float(yi);
}
// sum over the 16 lanes of a DPP row (our d dimension = lane&15)
__device__ __forceinline__ float row16_allreduce(float x) {
    x = dpp_ror_add<0x128>(x);   // row_ror:8
    x = dpp_ror_add<0x124>(x);   // row_ror:4
    x = dpp_ror_add<0x122>(x);   // row_ror:2
    x = dpp_ror_add<0x121>(x);   // row_ror:1
    return x;
}
// sum over the 4 iq replicas (lane bits 4,5)
__device__ __forceinline__ float iq4_allreduce(float x) {
    x += __shfl_xor(x, 16);
    x += __shfl_xor(x, 32);
    return x;
}

__global__ __launch_bounds__(NT, 6)
void capsnet_kernel(const float* __restrict__ xg,
                    const float* __restrict__ cwg,
                    const float* __restrict__ lwg,
                    float* __restrict__ outg) {
    __shared__ float xs[M_BLK * 9];              //  288 B
    __shared__ float cw[288];                    // 1152 B
    __shared__ float caps_s[M_BLK * NI * CROW];  // 13824 B
    __shared__ float spl[2 * OC * NI * SROW];    // 57600 B (batch pair)
    __shared__ float el[2 * OC * NI];            //  2880 B exp(logits)
    __shared__ float sinvp[2 * 64];              //   512 B 1/sum_o exp, iq-padded
    // total ~76.3 KB -> 2 blocks/CU

    const int t  = threadIdx.x;
    const int b0 = blockIdx.x * M_BLK;

    if (t < M_BLK * 9) xs[t] = xg[b0 * 9 + t];
    if (t < 288)       cw[t] = cwg[t];

    // --- einsum-phase thread mapping: (eo, ei, edh), 720 active ---
    const bool act = t < 2 * OC * NI;
    const int eo  = t / 72;
    const int er  = t % 72;
    const int ei  = er >> 1;
    const int edh = er & 1;

    float4 w4[16];   // lin_w[eo][ei][edh*8..+7][0..7]
    if (act) {
        const float4* wp = reinterpret_cast<const float4*>(
            lwg + ((eo * NI + ei) * OD + edh * 8) * IL);
        #pragma unroll
        for (int j = 0; j < 16; ++j) w4[j] = wp[j];
    }

    // --- routing-phase thread mapping: wave = o, lane = (iq, d), 640 active ---
    const bool ract = t < OC * 64;
    const int ro  = t >> 6;          // wave id = out capsule
    const int lane = t & 63;
    const int rd  = lane & 15;       // d (DPP row dimension)
    const int riq = lane >> 4;       // i quarter: owns i = riq*9 + k

    __syncthreads();

    // ---- conv (1->32ch, 3x3, pad 1) + squash -> caps_s ----
    if (t < M_BLK * NI) {   // 288
        const int m  = t / NI;
        const int ci = t % NI;
        const int cg = ci & 3;
        const int wx = (ci >> 2) % 3;
        const int hx = ci / 12;
        float acc[IL] = {0.f,0.f,0.f,0.f,0.f,0.f,0.f,0.f};
        #pragma unroll
        for (int kh = 0; kh < 3; ++kh) {
            const int xh = hx + kh - 1;
            if (xh < 0 || xh > 2) continue;
            #pragma unroll
            for (int kw = 0; kw < 3; ++kw) {
                const int xw = wx + kw - 1;
                if (xw < 0 || xw > 2) continue;
                const float xv = xs[m * 9 + xh * 3 + xw];
                #pragma unroll
                for (int l = 0; l < IL; ++l)
                    acc[l] += xv * cw[(cg * 8 + l) * 9 + kh * 3 + kw];
            }
        }
        float n2 = 0.f;
        #pragma unroll
        for (int l = 0; l < IL; ++l) n2 += acc[l] * acc[l];
        const float sc = n2 / (1.f + n2) * rsqrtf(n2 + 1e-8f);
        float4* cp = reinterpret_cast<float4*>(caps_s + (m * NI + ci) * CROW);
        cp[0] = make_float4(acc[0]*sc, acc[1]*sc, acc[2]*sc, acc[3]*sc);
        cp[1] = make_float4(acc[4]*sc, acc[5]*sc, acc[6]*sc, acc[7]*sc);
    }
    __syncthreads();

    for (int pr = 0; pr < M_BLK / 2; ++pr) {
        // ---- E: einsum for batch pair -> spl[0], spl[1] ----
        if (act) {
            #pragma unroll
            for (int bp = 0; bp < 2; ++bp) {
                const float4* cp = reinterpret_cast<const float4*>(
                    caps_s + ((pr * 2 + bp) * NI + ei) * CROW);
                const float4 c0 = cp[0], c1 = cp[1];
                float Pv[8];
                #pragma unroll
                for (int d8 = 0; d8 < 8; ++d8) {
                    const float4 a = w4[2*d8], b = w4[2*d8 + 1];
                    Pv[d8] = a.x*c0.x + a.y*c0.y + a.z*c0.z + a.w*c0.w
                           + b.x*c1.x + b.y*c1.y + b.z*c1.z + b.w*c1.w;
                }
                float4* sp = reinterpret_cast<float4*>(
                    spl + bp * OC * NI * SROW + (eo * NI + ei) * SROW + edh * 8);
                sp[0] = make_float4(Pv[0], Pv[1], Pv[2], Pv[3]);
                sp[1] = make_float4(Pv[4], Pv[5], Pv[6], Pv[7]);
            }
        }
        __syncthreads();   // spl ready

        float P[2][9], lg[2][9];
        // ---- T + R0: transpose-read into regs, it0, agreement0, el write ----
        if (ract) {
            #pragma unroll
            for (int bp = 0; bp < 2; ++bp) {
                const float* sb = spl + bp * OC * NI * SROW
                                + (ro * NI + riq * 9) * SROW + rd;
                #pragma unroll
                for (int k = 0; k < 9; ++k) P[bp][k] = sb[k * SROW];
                float tl = 0.f;
                #pragma unroll
                for (int k = 0; k < 9; ++k) tl += P[bp][k];
                const float s  = 0.1f * iq4_allreduce(tl);   // softmax(0) = 1/10
                const float n2 = row16_allreduce(s * s);
                const float sc = n2 / (1.f + n2) * rsqrtf(n2 + 1e-8f);
                const float v  = s * sc;
                #pragma unroll
                for (int k = 0; k < 9; ++k)
                    lg[bp][k] = row16_allreduce(P[bp][k] * v);
                if (rd < 9)
                    el[bp * 360 + ro * NI + riq * 9 + rd] = __expf(lg[bp][rd]);
            }
        }
        __syncthreads();   // el ready
        // ---- S1: softmax denominators ----
        if (t < 72) {
            const int bp = t / NI, i = t % NI;
            float ss = 0.f;
            #pragma unroll
            for (int o2 = 0; o2 < OC; ++o2) ss += el[bp * 360 + o2 * NI + i];
            sinvp[bp * 64 + (i / 9) * 16 + (i % 9)] = 1.f / ss;
        }
        __syncthreads();   // sinv ready
        // ---- R1: it1 + agreement1 + el write ----
        if (ract) {
            #pragma unroll
            for (int bp = 0; bp < 2; ++bp) {
                const float* svp = sinvp + bp * 64 + riq * 16;
                float tl = 0.f;
                #pragma unroll
                for (int k = 0; k < 9; ++k)
                    tl += __expf(lg[bp][k]) * svp[k] * P[bp][k];
                const float s  = iq4_allreduce(tl);
                const float n2 = row16_allreduce(s * s);
                const float sc = n2 / (1.f + n2) * rsqrtf(n2 + 1e-8f);
                const float v  = s * sc;
                #pragma unroll
                for (int k = 0; k < 9; ++k)
                    lg[bp][k] += row16_allreduce(P[bp][k] * v);
                if (rd < 9)
                    el[bp * 360 + ro * NI + riq * 9 + rd] = __expf(lg[bp][rd]);
            }
        }
        __syncthreads();   // el ready
        // ---- S2 ----
        if (t < 72) {
            const int bp = t / NI, i = t % NI;
            float ss = 0.f;
            #pragma unroll
            for (int o2 = 0; o2 < OC; ++o2) ss += el[bp * 360 + o2 * NI + i];
            sinvp[bp * 64 + (i / 9) * 16 + (i % 9)] = 1.f / ss;
        }
        __syncthreads();   // sinv ready
        // ---- R2: it2 + output ----
        if (ract) {
            #pragma unroll
            for (int bp = 0; bp < 2; ++bp) {
                const float* svp = sinvp + bp * 64 + riq * 16;
                float tl = 0.f;
                #pragma unroll
                for (int k = 0; k < 9; ++k)
                    tl += __expf(lg[bp][k]) * svp[k] * P[bp][k];
                const float s  = iq4_allreduce(tl);
                const float n2 = row16_allreduce(s * s);
                const float sc = n2 / (1.f + n2) * rsqrtf(n2 + 1e-8f);
                const float v  = s * sc;
                if (riq == 0)
                    outg[(b0 + pr * 2 + bp) * (OC * OD) + ro * OD + rd] = v;
            }
        }
    }
}

extern "C" void kernel_launch(void* const* d_in, const int* in_sizes, int n_in,
                              void* d_out, int out_size, void* d_ws, size_t ws_size,
                              hipStream_t stream) {
    const float* x   = (const float*)d_in[0];   // [B,1,3,3]
    const float* cwp = (const float*)d_in[1];   // [32,1,3,3]
    const float* lw  = (const float*)d_in[2];   // [10,36,16,8]
    float* out = (float*)d_out;                 // [B,10,16]
    const int B = in_sizes[0] / 9;              // 16384
    dim3 grid(B / M_BLK), block(NT);
    capsnet_kernel<<<grid, block, 0, stream>>>(x, cwp, lw, out);
}